// Round 3
// baseline (287.505 us; speedup 1.0000x reference)
//
#include <hip/hip_runtime.h>

#define NUM_BINS 15
#define NCOLS 200            // classes
#define CHUNK 40             // columns per chunk (200 = 5 x 40, no ragged tail)
#define NCHUNK 5
#define ROWS_PER_BLOCK 256
#define BLOCK 256
#define F4_PER_THREAD 10     // ROWS_PER_BLOCK * CHUNK / 4 / BLOCK
#define LDS_ROW_F4 12        // 48 floats/row: 40 data + 8 pad -> lane stride 48 ≡ 16 mod 32 -> 2-way (free)

// Thread-per-row ECE main kernel with LDS transpose staging.
// Each block owns 256 rows. Per column-chunk: coalesced float4 global loads
// (prefetched one chunk ahead into registers) -> LDS tile -> each thread
// scalar-reduces its own row (online max/argmax/sum-exp). No cross-lane ops.
__global__ __launch_bounds__(BLOCK, 3) void ece_main_kernel(
    const float* __restrict__ logits,
    const int* __restrict__ targs,
    double* __restrict__ g_conf,      // [NUM_BINS]
    unsigned int* __restrict__ g_cnt, // [NUM_BINS]
    unsigned int* __restrict__ g_acc, // [NUM_BINS]
    int N)
{
    __shared__ float4 tile[ROWS_PER_BLOCK * LDS_ROW_F4];   // 48 KB
    __shared__ float s_conf[NUM_BINS];
    __shared__ unsigned int s_cnt[NUM_BINS];
    __shared__ unsigned int s_acc[NUM_BINS];

    const int t = threadIdx.x;
    if (t < NUM_BINS) { s_conf[t] = 0.0f; s_cnt[t] = 0u; s_acc[t] = 0u; }
    // (visibility of bin init is covered by the first __syncthreads below)

    const long long r0 = (long long)blockIdx.x * ROWS_PER_BLOCK;

    // Per-thread load geometry: f4_id = k*BLOCK + t -> (row, c4) within the
    // 256-row x 40-col chunk. Row-base pointers are chunk-independent.
    const float* rowbase[F4_PER_THREAD];
    int srow[F4_PER_THREAD], sc4[F4_PER_THREAD];
    #pragma unroll
    for (int k = 0; k < F4_PER_THREAD; ++k) {
        int id = k * BLOCK + t;
        int row = id / F4_PER_THREAD;          // 0..255
        int c4  = id - row * F4_PER_THREAD;    // 0..9
        long long rg = r0 + row;
        if (rg > N - 1) rg = N - 1;            // clamp (harmless dup reads on tail)
        rowbase[k] = logits + (size_t)rg * NCOLS + c4 * 4;
        srow[k] = row; sc4[k] = c4;
    }

    // Prefetch chunk 0 into registers.
    float4 p[F4_PER_THREAD];
    #pragma unroll
    for (int k = 0; k < F4_PER_THREAD; ++k)
        p[k] = *reinterpret_cast<const float4*>(rowbase[k]);

    float m = -INFINITY, s = 0.0f;
    int mi = 0;

    #pragma unroll
    for (int ch = 0; ch < NCHUNK; ++ch) {
        __syncthreads();   // prior compute done reading LDS (and bin-init visible)
        #pragma unroll
        for (int k = 0; k < F4_PER_THREAD; ++k)
            tile[srow[k] * LDS_ROW_F4 + sc4[k]] = p[k];
        __syncthreads();   // tile ready

        // Issue next chunk's global loads; they drain under this chunk's compute.
        if (ch + 1 < NCHUNK) {
            #pragma unroll
            for (int k = 0; k < F4_PER_THREAD; ++k)
                p[k] = *reinterpret_cast<const float4*>(rowbase[k] + (ch + 1) * CHUNK);
        }

        // Scalar reduce of my own row from LDS (stride 48 floats: 2-way, free).
        float4 q[F4_PER_THREAD];
        #pragma unroll
        for (int j = 0; j < F4_PER_THREAD; ++j)
            q[j] = tile[t * LDS_ROW_F4 + j];

        // chunk max + first-occurrence argmax (strict > keeps earliest index)
        float cm = -INFINITY; int ci = 0;
        #pragma unroll
        for (int j = 0; j < F4_PER_THREAD; ++j) {
            int base = ch * CHUNK + j * 4;
            if (q[j].x > cm) { cm = q[j].x; ci = base; }
            if (q[j].y > cm) { cm = q[j].y; ci = base + 1; }
            if (q[j].z > cm) { cm = q[j].z; ci = base + 2; }
            if (q[j].w > cm) { cm = q[j].w; ci = base + 3; }
        }
        // online-softmax rescale (first chunk: s=0, expf(-inf)=0 -> s stays 0)
        if (cm > m) { s *= __expf(m - cm); m = cm; mi = ci; }
        float ls = 0.0f;
        #pragma unroll
        for (int j = 0; j < F4_PER_THREAD; ++j) {
            ls += __expf(q[j].x - m) + __expf(q[j].y - m)
                + __expf(q[j].z - m) + __expf(q[j].w - m);
        }
        s += ls;
    }

    // Per-row result -> per-block bins.
    float conf = 1.0f / s;                          // max softmax prob
    int b = (int)ceilf(conf * (float)NUM_BINS) - 1; // torch-style (lo, hi] bins
    b = min(max(b, 0), NUM_BINS - 1);

    long long rg = r0 + t;
    if (rg < N) {
        atomicAdd(&s_conf[b], conf);
        atomicAdd(&s_cnt[b], 1u);
        if (mi == targs[rg]) atomicAdd(&s_acc[b], 1u);
    }

    __syncthreads();
    if (t < NUM_BINS) {
        unsigned int c = s_cnt[t];
        if (c > 0u) {
            atomicAdd(&g_cnt[t], c);
            atomicAdd(&g_acc[t], s_acc[t]);
            atomicAdd(&g_conf[t], (double)s_conf[t]);
        }
    }
}

// Final reduction over the 15 bins -> ece scalar.
__global__ void ece_final_kernel(
    const double* __restrict__ g_conf,
    const unsigned int* __restrict__ g_cnt,
    const unsigned int* __restrict__ g_acc,
    float* __restrict__ out,
    int N)
{
    const int t = threadIdx.x;
    float part = 0.0f;
    if (t < NUM_BINS) {
        unsigned int c = g_cnt[t];
        if (c > 0u) {
            double dc = (double)c;
            double avg_conf = g_conf[t] / dc;
            double acc = (double)g_acc[t] / dc;
            double gap = fabs(avg_conf - acc);
            part = (float)(gap * (dc / (double)N));
        }
    }
    #pragma unroll
    for (int off = 32; off > 0; off >>= 1) part += __shfl_xor(part, off);
    if (t == 0) out[0] = part;
}

extern "C" void kernel_launch(void* const* d_in, const int* in_sizes, int n_in,
                              void* d_out, int out_size, void* d_ws, size_t ws_size,
                              hipStream_t stream) {
    const float* logits = (const float*)d_in[0];
    const int* targs = (const int*)d_in[1];   // jax int64 -> int32 on device (x64 disabled)
    const int N = in_sizes[1];                // 524288 rows

    // workspace: double conf[15] | u32 cnt[15] | u32 acc[15]
    double* g_conf = (double*)d_ws;
    unsigned int* g_cnt = (unsigned int*)(g_conf + NUM_BINS);
    unsigned int* g_acc = g_cnt + NUM_BINS;
    const size_t ws_used = NUM_BINS * (sizeof(double) + 2 * sizeof(unsigned int));

    hipMemsetAsync(d_ws, 0, ws_used, stream);

    const int grid = (N + ROWS_PER_BLOCK - 1) / ROWS_PER_BLOCK;  // 2048
    ece_main_kernel<<<grid, BLOCK, 0, stream>>>(logits, targs, g_conf, g_cnt, g_acc, N);
    ece_final_kernel<<<1, 64, 0, stream>>>(g_conf, g_cnt, g_acc, (float*)d_out, N);
}

// Round 4
// 87.464 us; speedup vs baseline: 3.2871x; 3.2871x over previous
//
#include <hip/hip_runtime.h>

#define NUM_BINS 15
#define NCOLS 200
#define ROWS_PER_BLOCK 64
#define BLOCK 256
#define F4_PER_ROW (NCOLS / 4)                    // 50
#define TILE_F4 (ROWS_PER_BLOCK * F4_PER_ROW)     // 3200 f4 = 51200 B

__device__ __forceinline__ float max4(float4 q) {
    return fmaxf(fmaxf(q.x, q.y), fmaxf(q.z, q.w));
}
__device__ __forceinline__ float exp4sum(float4 q, float m) {
    return __expf(q.x - m) + __expf(q.y - m) + __expf(q.z - m) + __expf(q.w - m);
}

// Persistent blocks; per tile: 64 rows (50 KB) staged global->LDS with
// global_load_lds (no VGPR staging -> no spill; contiguous -> no over-fetch).
// One quad per row; lane sub owns f4 columns {sub, sub+4, ...} -> b128 LDS
// reads hit 2 lanes per 4-bank window (conflict-free minimum).
__global__ __launch_bounds__(BLOCK) void ece_main_kernel(
    const float* __restrict__ logits,
    const int* __restrict__ targs,
    double* __restrict__ g_conf,      // [NUM_BINS]
    unsigned int* __restrict__ g_cnt, // [NUM_BINS]
    unsigned int* __restrict__ g_acc, // [NUM_BINS]
    int N)
{
    __shared__ float4 tile[TILE_F4];              // 50 KB
    __shared__ float s_conf[NUM_BINS];
    __shared__ unsigned int s_cnt[NUM_BINS];
    __shared__ unsigned int s_acc[NUM_BINS];

    const int t = threadIdx.x;
    if (t < NUM_BINS) { s_conf[t] = 0.0f; s_cnt[t] = 0u; s_acc[t] = 0u; }

    const int wavebase = t & ~63;                 // wave-uniform LDS base part
    const int gmax = N * F4_PER_ROW - 1;          // last valid global f4 index
    const int row = t >> 2;                       // 0..63  (quad id = my row)
    const int sub = t & 3;                        // lane within quad
    const int qbase = row * F4_PER_ROW;
    const int NT = gridDim.x;

    // ---- stage one 64-row tile: 13 wave-level global_load_lds rounds
    //      (12 full + 1 half: slots 3072..3199 -> waves 0,1 only)
    auto issue_tile = [&](int ti) {
        const int sbase = ti * TILE_F4;
        #pragma unroll
        for (int k = 0; k < 13; ++k) {
            if (k < 12 || wavebase < (TILE_F4 - 12 * BLOCK)) {
                int sg = sbase + k * BLOCK + t;   // global f4 index (linear copy)
                sg = min(sg, gmax);
                const float* g = logits + (size_t)sg * 4;
                __builtin_amdgcn_global_load_lds(
                    (const __attribute__((address_space(1))) void*)g,
                    (__attribute__((address_space(3))) void*)&tile[k * BLOCK + wavebase],
                    16, 0, 0);
            }
        }
    };

    int ti = blockIdx.x;
    issue_tile(ti);

    int rowg = ti * ROWS_PER_BLOCK + row;
    int tg = (sub == 0 && rowg < N) ? targs[rowg] : 0;   // prefetch first targ

    for (;;) {
        __syncthreads();   // compiler drains vmcnt(0) before s_barrier: tile ready
                           // (also covers bin-init visibility on first pass)

        // ---- read phase: my 13 f4s + target logit into registers
        float4 q[13];
        #pragma unroll
        for (int j = 0; j < 12; ++j) q[j] = tile[qbase + sub + 4 * j];
        q[12] = tile[qbase + min(sub + 48, F4_PER_ROW - 1)];  // clamp: dup for sub>=2

        float tl = 0.0f;
        if (sub == 0) tl = ((const float*)tile)[row * NCOLS + tg];

        __syncthreads();   // all reads done: safe to overwrite tile

        // ---- issue next tile's loads (latency hides under compute below)
        const int tn = ti + NT;
        const bool more = tn * ROWS_PER_BLOCK < N;
        if (more) issue_tile(tn);

        int tg_next = 0;
        if (more && sub == 0) {
            int rn = tn * ROWS_PER_BLOCK + row;
            if (rn < N) tg_next = targs[rn];
        }

        // ---- compute: row max (dups harmless), then sum of exp
        float m = max4(q[0]);
        #pragma unroll
        for (int j = 1; j < 13; ++j) m = fmaxf(m, max4(q[j]));

        float s = 0.0f;
        #pragma unroll
        for (int j = 0; j < 12; ++j) s += exp4sum(q[j], m);
        if (sub < 2) s += exp4sum(q[12], m);      // mask the clamped duplicate

        // quad combine: exact max + rescaled sums (2 butterfly steps)
        #pragma unroll
        for (int off = 1; off <= 2; off <<= 1) {
            float om = __shfl_xor(m, off);
            float os = __shfl_xor(s, off);
            float M = fmaxf(m, om);
            s = s * __expf(m - M) + os * __expf(om - M);
            m = M;
        }

        if (sub == 0 && rowg < N) {
            float conf = 1.0f / s;                            // max softmax prob
            int b = (int)ceilf(conf * (float)NUM_BINS) - 1;   // torch (lo, hi] bins
            b = min(max(b, 0), NUM_BINS - 1);
            atomicAdd(&s_conf[b], conf);
            atomicAdd(&s_cnt[b], 1u);
            if (tl == m) atomicAdd(&s_acc[b], 1u);            // pred == targ
        }

        if (!more) break;
        ti = tn;
        rowg = ti * ROWS_PER_BLOCK + row;
        tg = tg_next;
    }

    __syncthreads();
    if (t < NUM_BINS) {
        unsigned int c = s_cnt[t];
        if (c > 0u) {
            atomicAdd(&g_cnt[t], c);
            atomicAdd(&g_acc[t], s_acc[t]);
            atomicAdd(&g_conf[t], (double)s_conf[t]);
        }
    }
}

// Final reduction over the 15 bins -> ece scalar.
__global__ void ece_final_kernel(
    const double* __restrict__ g_conf,
    const unsigned int* __restrict__ g_cnt,
    const unsigned int* __restrict__ g_acc,
    float* __restrict__ out,
    int N)
{
    const int t = threadIdx.x;
    float part = 0.0f;
    if (t < NUM_BINS) {
        unsigned int c = g_cnt[t];
        if (c > 0u) {
            double dc = (double)c;
            double avg_conf = g_conf[t] / dc;
            double acc = (double)g_acc[t] / dc;
            double gap = fabs(avg_conf - acc);
            part = (float)(gap * (dc / (double)N));
        }
    }
    #pragma unroll
    for (int off = 32; off > 0; off >>= 1) part += __shfl_xor(part, off);
    if (t == 0) out[0] = part;
}

extern "C" void kernel_launch(void* const* d_in, const int* in_sizes, int n_in,
                              void* d_out, int out_size, void* d_ws, size_t ws_size,
                              hipStream_t stream) {
    const float* logits = (const float*)d_in[0];
    const int* targs = (const int*)d_in[1];   // jax int64 -> int32 on device (x64 disabled)
    const int N = in_sizes[1];                // 524288 rows

    // workspace: double conf[15] | u32 cnt[15] | u32 acc[15]
    double* g_conf = (double*)d_ws;
    unsigned int* g_cnt = (unsigned int*)(g_conf + NUM_BINS);
    unsigned int* g_acc = g_cnt + NUM_BINS;
    const size_t ws_used = NUM_BINS * (sizeof(double) + 2 * sizeof(unsigned int));

    hipMemsetAsync(d_ws, 0, ws_used, stream);

    const int total_tiles = (N + ROWS_PER_BLOCK - 1) / ROWS_PER_BLOCK;  // 8192
    const int grid = min(total_tiles, 768);   // 3 blocks/CU (LDS-capped), persistent
    ece_main_kernel<<<grid, BLOCK, 0, stream>>>(logits, targs, g_conf, g_cnt, g_acc, N);
    ece_final_kernel<<<1, 64, 0, stream>>>(g_conf, g_cnt, g_acc, (float*)d_out, N);
}

// Round 5
// 85.037 us; speedup vs baseline: 3.3809x; 1.0285x over previous
//
#include <hip/hip_runtime.h>

#define NUM_BINS 15
#define NCOLS 200
#define BLOCK 256
#define LANES_PER_ROW 8            // octet per row
#define ROWS_PER_BLOCK_ITER (BLOCK / LANES_PER_ROW)   // 32
#define GRID 1024                  // 4 blocks/CU, grid-stride persistent
#define NREP 16                    // replica slots for global bin flush

__device__ __forceinline__ float max4(float4 q) {
    return fmaxf(fmaxf(q.x, q.y), fmaxf(q.z, q.w));
}
__device__ __forceinline__ float exp4sum(float4 q, float m) {
    return __expf(q.x - m) + __expf(q.y - m) + __expf(q.z - m) + __expf(q.w - m);
}

// Octet-per-row, direct-to-register streaming (no LDS staging, no barriers in
// the loop). Lane sub of each octet owns f4 columns {sub, 8+sub, ..., 40+sub}
// (+ {48+sub} for sub<2): load j is a contiguous 128B chunk per octet ->
// well-coalesced dwordx4. Row reduce: per-lane max, 3-step shfl_xor max,
// per-lane sum(exp(x - rowmax)), 3-step shfl_xor sum. Exact row max also
// serves the accuracy check (logit[targ] == max).
__global__ __launch_bounds__(BLOCK) void ece_main_kernel(
    const float* __restrict__ logits,
    const int* __restrict__ targs,
    double* __restrict__ g_conf,      // [NREP][NUM_BINS]
    unsigned int* __restrict__ g_cnt, // [NREP][NUM_BINS]
    unsigned int* __restrict__ g_acc, // [NREP][NUM_BINS]
    int N)
{
    __shared__ float s_conf[NUM_BINS];
    __shared__ unsigned int s_cnt[NUM_BINS];
    __shared__ unsigned int s_acc[NUM_BINS];

    const int t = threadIdx.x;
    if (t < NUM_BINS) { s_conf[t] = 0.0f; s_cnt[t] = 0u; s_acc[t] = 0u; }
    __syncthreads();

    const int lrow = t >> 3;          // 0..31: row within block-iteration
    const int sub = t & 7;            // lane within octet
    const int stride = GRID * ROWS_PER_BLOCK_ITER;

    int row = blockIdx.x * ROWS_PER_BLOCK_ITER + lrow;

    // prefetch first iteration's target index (breaks targ->logit load chain)
    int tg = 0;
    if (sub == 0 && row < N) tg = targs[row];

    for (; row < N; row += stride) {
        const float* rp = logits + (size_t)row * NCOLS + sub * 4;

        // 6 full f4 loads (covers f4 0..47) + 1 partial (f4 48,49 on sub<2).
        // Offsets 0,128,...,640 bytes from one base -> offset:N folding.
        float4 q0 = *reinterpret_cast<const float4*>(rp);
        float4 q1 = *reinterpret_cast<const float4*>(rp + 32);
        float4 q2 = *reinterpret_cast<const float4*>(rp + 64);
        float4 q3 = *reinterpret_cast<const float4*>(rp + 96);
        float4 q4 = *reinterpret_cast<const float4*>(rp + 128);
        float4 q5 = *reinterpret_cast<const float4*>(rp + 160);
        const bool has7 = (sub < 2);
        float4 q6 = make_float4(-INFINITY, -INFINITY, -INFINITY, -INFINITY);
        if (has7) q6 = *reinterpret_cast<const float4*>(rp + 192);  // f4 48+sub

        // target logit for THIS row (tg prefetched) + next row's target index
        float tl = 0.0f;
        int tg_next = 0;
        if (sub == 0) {
            tl = logits[(size_t)row * NCOLS + tg];
            int rn = row + stride;
            if (rn < N) tg_next = targs[rn];
        }

        // per-lane max, then exact octet max (xor 1,2,4 stays in the octet)
        float m = fmaxf(fmaxf(max4(q0), max4(q1)),
                        fmaxf(fmaxf(max4(q2), max4(q3)),
                              fmaxf(max4(q4), max4(q5))));
        if (has7) m = fmaxf(m, max4(q6));
        m = fmaxf(m, __shfl_xor(m, 1));
        m = fmaxf(m, __shfl_xor(m, 2));
        m = fmaxf(m, __shfl_xor(m, 4));

        // sum of exp(x - rowmax); q6 lanes without data contribute 0 via guard
        float s = exp4sum(q0, m) + exp4sum(q1, m) + exp4sum(q2, m)
                + exp4sum(q3, m) + exp4sum(q4, m) + exp4sum(q5, m);
        if (has7) s += exp4sum(q6, m);
        s += __shfl_xor(s, 1);
        s += __shfl_xor(s, 2);
        s += __shfl_xor(s, 4);

        if (sub == 0) {
            float conf = 1.0f / s;                            // max softmax prob
            int b = (int)ceilf(conf * (float)NUM_BINS) - 1;   // torch (lo, hi] bins
            b = min(max(b, 0), NUM_BINS - 1);
            atomicAdd(&s_conf[b], conf);
            atomicAdd(&s_cnt[b], 1u);
            if (tl == m) atomicAdd(&s_acc[b], 1u);            // pred == targ
        }
        tg = tg_next;
    }

    __syncthreads();
    if (t < NUM_BINS) {
        unsigned int c = s_cnt[t];
        if (c > 0u) {
            const int rep = blockIdx.x & (NREP - 1);          // cap atomic chains
            atomicAdd(&g_cnt[rep * NUM_BINS + t], c);
            atomicAdd(&g_acc[rep * NUM_BINS + t], s_acc[t]);
            atomicAdd(&g_conf[rep * NUM_BINS + t], (double)s_conf[t]);
        }
    }
}

// Final reduction: sum 16 replicas per bin, then ece scalar.
__global__ void ece_final_kernel(
    const double* __restrict__ g_conf,
    const unsigned int* __restrict__ g_cnt,
    const unsigned int* __restrict__ g_acc,
    float* __restrict__ out,
    int N)
{
    const int t = threadIdx.x;
    float part = 0.0f;
    if (t < NUM_BINS) {
        double conf = 0.0;
        unsigned long long cnt = 0, acc = 0;
        #pragma unroll
        for (int r = 0; r < NREP; ++r) {
            conf += g_conf[r * NUM_BINS + t];
            cnt  += g_cnt[r * NUM_BINS + t];
            acc  += g_acc[r * NUM_BINS + t];
        }
        if (cnt > 0) {
            double dc = (double)cnt;
            double gap = fabs(conf / dc - (double)acc / dc);
            part = (float)(gap * (dc / (double)N));
        }
    }
    #pragma unroll
    for (int off = 32; off > 0; off >>= 1) part += __shfl_xor(part, off);
    if (t == 0) out[0] = part;
}

extern "C" void kernel_launch(void* const* d_in, const int* in_sizes, int n_in,
                              void* d_out, int out_size, void* d_ws, size_t ws_size,
                              hipStream_t stream) {
    const float* logits = (const float*)d_in[0];
    const int* targs = (const int*)d_in[1];   // jax int64 -> int32 on device (x64 disabled)
    const int N = in_sizes[1];                // 524288 rows

    // workspace: double conf[16][15] | u32 cnt[16][15] | u32 acc[16][15]
    double* g_conf = (double*)d_ws;
    unsigned int* g_cnt = (unsigned int*)(g_conf + NREP * NUM_BINS);
    unsigned int* g_acc = g_cnt + NREP * NUM_BINS;
    const size_t ws_used = NREP * NUM_BINS * (sizeof(double) + 2 * sizeof(unsigned int));

    hipMemsetAsync(d_ws, 0, ws_used, stream);

    const int total_groups = (N + ROWS_PER_BLOCK_ITER - 1) / ROWS_PER_BLOCK_ITER;
    const int grid = min(total_groups, GRID);
    ece_main_kernel<<<grid, BLOCK, 0, stream>>>(logits, targs, g_conf, g_cnt, g_acc, N);
    ece_final_kernel<<<1, 64, 0, stream>>>(g_conf, g_cnt, g_acc, (float*)d_out, N);
}